// Round 2
// baseline (234.572 us; speedup 1.0000x reference)
//
#include <hip/hip_runtime.h>
#include <cstdint>
#include <cstddef>

// Sparse submanifold 3x3x3 conv, C_in=C_out=64, fp32. SHAPE=(256,256,256), BS=2
// -> packed key = (b<<24)|(x<<16)|(y<<8)|z.
//
// center tap (k=13): dense 200K x 64 @ 64 x 64 GEMM via bf16 MFMA
// (16x16x32), W13 pre-packed into fragment order. Non-center taps (~31K
// pairs): probe kernel compacts (site,k,nbi) with LDS-aggregated counters,
// conv_pairs accumulates via fp32 atomics.
//
// R1: 13 offsets (mutual-neighbor symmetry, emit both directions per hit).
// R2(this): probe decomposition flipped from one-thread-per-site to
// one-thread-per-(site,offset): 16 lanes/site (13 active), 16 sites/block
// -> 12.5K blocks (~49/CU). R1 counters showed 24% occupancy (782 blocks =
// 3/CU) with 9% VALU — latency-bound with too few waves to hide the probe
// round-trip; TLP, not per-thread MLP, is the lever. Worst case 416
// pairs/block means LCAP=416 is exact — spill path deleted, LDS 8.7->3.3KB.

typedef __attribute__((ext_vector_type(8))) short bf16x8;
typedef __attribute__((ext_vector_type(4))) float f32x4;

static constexpr unsigned EMPTY_KEY = 0xFFFFFFFFu;
static constexpr int LCAP = 416;   // 16 sites * 13 offsets * 2 pairs (exact)

__device__ __forceinline__ unsigned hash_mix(unsigned key) {
    unsigned h = key * 0x9E3779B1u;
    h ^= h >> 15;
    return h;
}

__device__ __forceinline__ unsigned short f2bf(float x) {  // RNE fp32->bf16
    unsigned u = __builtin_bit_cast(unsigned, x);
    return (unsigned short)((u + 0x7FFFu + ((u >> 16) & 1u)) >> 16);
}

// init: clear hash keys, zero pair counter, build W13 bf16 fragment table.
// wfrag entry e = (ks*4 + nt)*64 + lane, elem j = bf16(W13[ks*32+(lane>>4)*8+j]
// [nt*16+(lane&15)]).
__global__ void init_table_kernel(unsigned* __restrict__ keys, int nslots,
                                  unsigned* __restrict__ cnt,
                                  const float* __restrict__ weight,
                                  unsigned short* __restrict__ wfrag) {
    int i = blockIdx.x * blockDim.x + threadIdx.x;
    if (i < nslots) keys[i] = EMPTY_KEY;
    if (i == 0) *cnt = 0u;
    if (i < 512) {
        const int lane = i & 63, nt = (i >> 6) & 3, ks = i >> 8;
        const float* __restrict__ w13 = weight + 13 * 4096;
        #pragma unroll
        for (int j = 0; j < 8; ++j) {
            const int k = ks * 32 + (lane >> 4) * 8 + j;
            const int n = nt * 16 + (lane & 15);
            wfrag[(size_t)i * 8 + j] = f2bf(w13[k * 64 + n]);
        }
    }
}

__global__ void insert_kernel(const int4* __restrict__ coords, int n,
                              unsigned* __restrict__ keys,
                              unsigned* __restrict__ vals, unsigned mask) {
    int i = blockIdx.x * blockDim.x + threadIdx.x;
    if (i >= n) return;
    const int4 c = coords[i];   // (b, x, y, z)
    const unsigned key = ((unsigned)c.x << 24) | ((unsigned)c.y << 16) |
                         ((unsigned)c.z << 8) | (unsigned)c.w;
    unsigned s = hash_mix(key) & mask;
    while (true) {
        unsigned prev = atomicCAS(&keys[s], EMPTY_KEY, key);
        if (prev == EMPTY_KEY) { vals[s] = (unsigned)i; break; }
        s = (s + 1) & mask;   // coords unique -> no duplicate keys
    }
}

// One thread per (site, offset): 16 lanes/site (k<13 active), 16 sites/block.
// Each hit emits (site,k,nbi) AND the mirror (nbi,26-k,site) into LDS;
// one global atomicAdd per block flushes. Worst case fits LCAP exactly.
__global__ __launch_bounds__(256) void probe_pairs_kernel(
    const int4* __restrict__ coords, int n,
    const unsigned* __restrict__ keys, const unsigned* __restrict__ vals,
    unsigned mask, unsigned* __restrict__ cnt, uint2* __restrict__ pairs,
    unsigned cap)
{
    __shared__ unsigned lcnt, lbase;
    __shared__ uint2 lbuf[LCAP];
    if (threadIdx.x == 0) lcnt = 0u;
    __syncthreads();

    const int k = threadIdx.x & 15;                    // offset id, 0..15
    const int site = blockIdx.x * 16 + (threadIdx.x >> 4);
    if (site < n && k < 13) {
        const int4 c = coords[site];
        const int dx = k / 9 - 1, dy = (k / 3) % 3 - 1, dz = k % 3 - 1;
        const int nx = c.y + dx, ny = c.z + dy, nz = c.w + dz;
        if (((nx | ny | nz) & ~255) == 0) {
            const unsigned key = ((unsigned)c.x << 24) | ((unsigned)nx << 16) |
                                 ((unsigned)ny << 8) | (unsigned)nz;
            unsigned s = hash_mix(key) & mask;
            while (true) {
                const unsigned kv = keys[s];
                if (kv == key) {
                    const unsigned nbi = vals[s];
                    const unsigned li = atomicAdd(&lcnt, 2u);
                    lbuf[li] = make_uint2(
                        (unsigned)site | ((unsigned)k << 18), nbi);
                    lbuf[li + 1] = make_uint2(
                        nbi | ((unsigned)(26 - k) << 18), (unsigned)site);
                    break;
                }
                if (kv == EMPTY_KEY) break;
                s = (s + 1) & mask;
            }
        }
    }

    __syncthreads();
    unsigned nloc = lcnt;
    if (nloc > (unsigned)LCAP) nloc = (unsigned)LCAP;   // defensive
    if (threadIdx.x == 0) lbase = atomicAdd(cnt, nloc);
    __syncthreads();
    const unsigned b0 = lbase;
    for (unsigned i = threadIdx.x; i < nloc; i += blockDim.x)
        if (b0 + i < cap) pairs[b0 + i] = lbuf[i];
}

// Dense center GEMM via MFMA: out = bias + feats @ W13.
// One wave per 16 sites x 64 oc. A: row=lane&15, k=(lane>>4)*8+j (+ks*32).
// B pre-packed in wfrag. C/D: col=lane&15, row=(lane>>4)*4+reg.
__global__ __launch_bounds__(256) void conv_center_mfma(
    const float* __restrict__ feats, const unsigned short* __restrict__ wfrag,
    const float* __restrict__ bias, float* __restrict__ out, int n)
{
    const int lane = threadIdx.x & 63;
    const int wid = blockIdx.x * (blockDim.x >> 6) + (threadIdx.x >> 6);
    const int s0 = wid * 16;
    if (s0 >= n) return;

    // B fragments: 2 ksteps x 4 ntiles, 16B per lane each
    bf16x8 bfrag[2][4];
    #pragma unroll
    for (int ks = 0; ks < 2; ++ks)
        #pragma unroll
        for (int nt = 0; nt < 4; ++nt)
            bfrag[ks][nt] = *reinterpret_cast<const bf16x8*>(
                wfrag + ((size_t)((ks * 4 + nt) * 64 + lane)) * 8);

    const int arow = s0 + (lane & 15);
    const bool vrow = arow < n;
    const float* __restrict__ fbase =
        feats + (size_t)(vrow ? arow : 0) * 64 + (lane >> 4) * 8;

    f32x4 acc[4] = {{0.f, 0.f, 0.f, 0.f}, {0.f, 0.f, 0.f, 0.f},
                    {0.f, 0.f, 0.f, 0.f}, {0.f, 0.f, 0.f, 0.f}};

    #pragma unroll
    for (int ks = 0; ks < 2; ++ks) {
        const f32x4 flo = *reinterpret_cast<const f32x4*>(fbase + ks * 32);
        const f32x4 fhi = *reinterpret_cast<const f32x4*>(fbase + ks * 32 + 4);
        bf16x8 afrag;
        afrag[0] = (short)f2bf(flo.x); afrag[1] = (short)f2bf(flo.y);
        afrag[2] = (short)f2bf(flo.z); afrag[3] = (short)f2bf(flo.w);
        afrag[4] = (short)f2bf(fhi.x); afrag[5] = (short)f2bf(fhi.y);
        afrag[6] = (short)f2bf(fhi.z); afrag[7] = (short)f2bf(fhi.w);
        #pragma unroll
        for (int nt = 0; nt < 4; ++nt)
            acc[nt] = __builtin_amdgcn_mfma_f32_16x16x32_bf16(
                afrag, bfrag[ks][nt], acc[nt], 0, 0, 0);
    }

    const int crow0 = s0 + (lane >> 4) * 4;
    const int col = lane & 15;
    #pragma unroll
    for (int nt = 0; nt < 4; ++nt) {
        const float bv = bias[nt * 16 + col];
        #pragma unroll
        for (int r = 0; r < 4; ++r) {
            const int sr = crow0 + r;
            if (sr < n)
                out[(size_t)sr * 64 + nt * 16 + col] = acc[nt][r] + bv;
        }
    }
}

// One wave per pair (grid-stride): out[site] += feats[nbi] @ W[k], fp32 atomics.
__global__ __launch_bounds__(256) void conv_pairs_kernel(
    const float* __restrict__ feats, const float* __restrict__ weight,
    const uint2* __restrict__ pairs, const unsigned* __restrict__ cnt_p,
    unsigned cap, float* __restrict__ out)
{
    const int lane = threadIdx.x & 63;
    const unsigned nw = (gridDim.x * blockDim.x) >> 6;
    const unsigned wid = blockIdx.x * (blockDim.x >> 6) + (threadIdx.x >> 6);
    unsigned cnt = *cnt_p;
    if (cnt > cap) cnt = cap;
    for (unsigned p = wid; p < cnt; p += nw) {
        const uint2 pr = pairs[p];
        const unsigned site = pr.x & 0x3FFFFu;
        const unsigned k = pr.x >> 18;
        const unsigned nbi = pr.y;
        const float4* __restrict__ fr =
            reinterpret_cast<const float4*>(feats + (size_t)nbi * 64);
        const float* __restrict__ wk = weight + (size_t)k * 4096;
        float a0 = 0.f, a1 = 0.f, a2 = 0.f, a3 = 0.f;
        #pragma unroll
        for (int q = 0; q < 16; ++q) {
            const float4 f = fr[q];
            a0 = fmaf(f.x, wk[(4 * q + 0) * 64 + lane], a0);
            a1 = fmaf(f.y, wk[(4 * q + 1) * 64 + lane], a1);
            a2 = fmaf(f.z, wk[(4 * q + 2) * 64 + lane], a2);
            a3 = fmaf(f.w, wk[(4 * q + 3) * 64 + lane], a3);
        }
        atomicAdd(&out[(size_t)site * 64 + lane], (a0 + a1) + (a2 + a3));
    }
}

extern "C" void kernel_launch(void* const* d_in, const int* in_sizes, int n_in,
                              void* d_out, int out_size, void* d_ws, size_t ws_size,
                              hipStream_t stream) {
    const float* feats  = (const float*)d_in[0];   // (N, 64)
    const int4*  coords = (const int4*)d_in[1];    // (N, 4)
    const float* weight = (const float*)d_in[2];   // (27, 64, 64)
    const float* bias   = (const float*)d_in[3];   // (64,)
    float* out = (float*)d_out;

    const int n = in_sizes[1] / 4;

    // ws layout: keys | vals | cnt (256B) | wfrag (8KB) | pairs
    const bool big = ws_size >= ((size_t)16 << 20);
    const int nslots = big ? (1 << 19) : (1 << 18);
    const unsigned mask = (unsigned)(nslots - 1);
    unsigned* keys = (unsigned*)d_ws;
    unsigned* vals = keys + nslots;
    unsigned* cnt  = vals + nslots;
    unsigned short* wfrag = (unsigned short*)((char*)cnt + 256);
    uint2* pairs = (uint2*)((char*)wfrag + 8192);
    const size_t used = (size_t)nslots * 8 + 256 + 8192;
    size_t cap_sz = (ws_size > used) ? (ws_size - used) / sizeof(uint2) : 0;
    if (cap_sz > (size_t)(4 << 20)) cap_sz = (size_t)(4 << 20);
    const unsigned cap = (unsigned)cap_sz;

    {
        int blocks = (nslots + 255) / 256;
        init_table_kernel<<<blocks, 256, 0, stream>>>(keys, nslots, cnt,
                                                      weight, wfrag);
    }
    {
        int blocks = (n + 255) / 256;
        insert_kernel<<<blocks, 256, 0, stream>>>(coords, n, keys, vals, mask);
    }
    {
        int blocks = (n + 15) / 16;   // 16 sites per block, 16 lanes per site
        probe_pairs_kernel<<<blocks, 256, 0, stream>>>(coords, n, keys, vals,
                                                       mask, cnt, pairs, cap);
    }
    {
        int waves = (n + 15) / 16;
        int blocks = (waves + 3) / 4;
        conv_center_mfma<<<blocks, 256, 0, stream>>>(feats, wfrag, bias, out, n);
    }
    {
        conv_pairs_kernel<<<1024, 256, 0, stream>>>(feats, weight, pairs, cnt,
                                                    cap, out);
    }
}

// Round 3
// 198.825 us; speedup vs baseline: 1.1798x; 1.1798x over previous
//
#include <hip/hip_runtime.h>
#include <cstdint>
#include <cstddef>

// Sparse submanifold 3x3x3 conv, C_in=C_out=64, fp32. SHAPE=(256,256,256), BS=2
// -> packed key = (b<<24)|(x<<16)|(y<<8)|z.
//
// center tap (k=13): dense 200K x 64 @ 64 x 64 GEMM via bf16 MFMA
// (16x16x32), W13 pre-packed into fragment order. Non-center taps (~31K
// hits -> ~62K pairs): probe kernel compacts (site,k,nbi) with
// LDS-aggregated counters, conv_pairs accumulates via fp32 atomics.
//
// R1: 13 offsets (mutual-neighbor symmetry, emit both directions per hit),
//     batched two-phase probing (all first-round hash loads in flight).
// R2: FAILED — 16 threads/site -> 12.5K blocks, each doing one same-address
//     global atomicAdd reservation. Counters: occ 72%, VALU 4%, WRITE_SIZE
//     +480KB ~= 12.5K atomic line writebacks. Same-address atomics
//     serialize ~20cyc in L2 -> ~110us chain dominated (152us).
// R3(this): 2 threads/site (7/6 offsets, keeps R1's MLP batching) -> 24
//     waves/CU (2x R1's TLP), 1563 blocks; reservation counter sharded 64
//     ways (block b -> cnts[b&63], pairs region b&63) so no atomic chain.

typedef __attribute__((ext_vector_type(8))) short bf16x8;
typedef __attribute__((ext_vector_type(4))) float f32x4;

static constexpr unsigned EMPTY_KEY = 0xFFFFFFFFu;
static constexpr int LCAP = 3328;   // 128 sites * 13 offsets * 2 (exact worst)
static constexpr unsigned NREG = 64;  // pair-buffer regions / counters

__device__ __forceinline__ unsigned hash_mix(unsigned key) {
    unsigned h = key * 0x9E3779B1u;
    h ^= h >> 15;
    return h;
}

__device__ __forceinline__ unsigned short f2bf(float x) {  // RNE fp32->bf16
    unsigned u = __builtin_bit_cast(unsigned, x);
    return (unsigned short)((u + 0x7FFFu + ((u >> 16) & 1u)) >> 16);
}

// init: clear hash keys, zero region counters, build W13 bf16 fragment table.
// wfrag entry e = (ks*4 + nt)*64 + lane, elem j = bf16(W13[ks*32+(lane>>4)*8+j]
// [nt*16+(lane&15)]).
__global__ void init_table_kernel(unsigned* __restrict__ keys, int nslots,
                                  unsigned* __restrict__ cnts,
                                  const float* __restrict__ weight,
                                  unsigned short* __restrict__ wfrag) {
    int i = blockIdx.x * blockDim.x + threadIdx.x;
    if (i < nslots) keys[i] = EMPTY_KEY;
    if (i < (int)NREG) cnts[i] = 0u;
    if (i < 512) {
        const int lane = i & 63, nt = (i >> 6) & 3, ks = i >> 8;
        const float* __restrict__ w13 = weight + 13 * 4096;
        #pragma unroll
        for (int j = 0; j < 8; ++j) {
            const int k = ks * 32 + (lane >> 4) * 8 + j;
            const int n = nt * 16 + (lane & 15);
            wfrag[(size_t)i * 8 + j] = f2bf(w13[k * 64 + n]);
        }
    }
}

__global__ void insert_kernel(const int4* __restrict__ coords, int n,
                              unsigned* __restrict__ keys,
                              unsigned* __restrict__ vals, unsigned mask) {
    int i = blockIdx.x * blockDim.x + threadIdx.x;
    if (i >= n) return;
    const int4 c = coords[i];   // (b, x, y, z)
    const unsigned key = ((unsigned)c.x << 24) | ((unsigned)c.y << 16) |
                         ((unsigned)c.z << 8) | (unsigned)c.w;
    unsigned s = hash_mix(key) & mask;
    while (true) {
        unsigned prev = atomicCAS(&keys[s], EMPTY_KEY, key);
        if (prev == EMPTY_KEY) { vals[s] = (unsigned)i; break; }
        s = (s + 1) & mask;   // coords unique -> no duplicate keys
    }
}

// Two threads per site: t=0 handles offsets 0..6, t=1 handles 7..12 (of the
// 13 k<13 offsets; each hit also emits the mirror (nbi,26-k,site)).
// Phase 1 issues all first-round hash loads independently (MLP); phase 2
// resolves with a rare serial continuation. Hits -> LDS; one reservation
// atomic per block on a 64-way sharded counter (R2 lesson: a single
// global counter serializes ~20cyc/block in L2).
__global__ __launch_bounds__(256) void probe_pairs_kernel(
    const int4* __restrict__ coords, int n,
    const unsigned* __restrict__ keys, const unsigned* __restrict__ vals,
    unsigned mask, unsigned* __restrict__ cnts, uint2* __restrict__ pairs,
    unsigned rcap)
{
    __shared__ unsigned lcnt, lbase;
    __shared__ uint2 lbuf[LCAP];
    if (threadIdx.x == 0) lcnt = 0u;
    __syncthreads();

    const int t = threadIdx.x & 1;
    const int site = (blockIdx.x * 256 + threadIdx.x) >> 1;
    if (site < n) {
        const int4 c = coords[site];
        const int k0 = t * 7;          // t=0: k=0..6, t=1: k=7..12
        const int nk = 7 - t;          // 7 or 6 active offsets
        unsigned kv[7];
        unsigned vmask = 0u;

        // phase 1: all first-round loads in flight (no inter-iter deps)
        #pragma unroll
        for (int j = 0; j < 7; ++j) {
            const int k = k0 + j;
            const int dx = k / 9 - 1, dy = (k / 3) % 3 - 1, dz = k % 3 - 1;
            const int nx = c.y + dx, ny = c.z + dy, nz = c.w + dz;
            const bool inb = (j < nk) && (((nx | ny | nz) & ~255) == 0);
            vmask |= inb ? (1u << j) : 0u;
            const unsigned key = ((unsigned)c.x << 24) | ((unsigned)nx << 16) |
                                 ((unsigned)ny << 8) | (unsigned)nz;
            kv[j] = inb ? keys[hash_mix(key) & mask] : EMPTY_KEY;
        }

        // phase 2: resolve (recompute key/slot to keep register pressure low)
        #pragma unroll
        for (int j = 0; j < 7; ++j) {
            if (!((vmask >> j) & 1u)) continue;
            const int k = k0 + j;
            const int dx = k / 9 - 1, dy = (k / 3) % 3 - 1, dz = k % 3 - 1;
            const unsigned key = ((unsigned)c.x << 24) |
                                 ((unsigned)(c.y + dx) << 16) |
                                 ((unsigned)(c.z + dy) << 8) |
                                 (unsigned)(c.w + dz);
            unsigned s = hash_mix(key) & mask;
            unsigned kvv = kv[j];
            while (kvv != EMPTY_KEY) {
                if (kvv == key) {
                    const unsigned nbi = vals[s];
                    const unsigned li = atomicAdd(&lcnt, 2u);
                    // worst case 128*13*2 == LCAP exactly -> no overflow
                    lbuf[li] = make_uint2(
                        (unsigned)site | ((unsigned)k << 18), nbi);
                    lbuf[li + 1] = make_uint2(
                        nbi | ((unsigned)(26 - k) << 18), (unsigned)site);
                    break;
                }
                s = (s + 1) & mask;
                kvv = keys[s];
            }
        }
    }

    __syncthreads();
    unsigned nloc = lcnt;
    if (nloc > (unsigned)LCAP) nloc = (unsigned)LCAP;   // defensive
    const unsigned reg = (unsigned)blockIdx.x & (NREG - 1u);
    if (threadIdx.x == 0) lbase = atomicAdd(&cnts[reg], nloc);
    __syncthreads();
    const unsigned b0 = lbase;
    uint2* __restrict__ rp = pairs + (size_t)reg * rcap;
    for (unsigned i = threadIdx.x; i < nloc; i += blockDim.x)
        if (b0 + i < rcap) rp[b0 + i] = lbuf[i];
}

// Dense center GEMM via MFMA: out = bias + feats @ W13.
// One wave per 16 sites x 64 oc. A: row=lane&15, k=(lane>>4)*8+j (+ks*32).
// B pre-packed in wfrag. C/D: col=lane&15, row=(lane>>4)*4+reg.
__global__ __launch_bounds__(256) void conv_center_mfma(
    const float* __restrict__ feats, const unsigned short* __restrict__ wfrag,
    const float* __restrict__ bias, float* __restrict__ out, int n)
{
    const int lane = threadIdx.x & 63;
    const int wid = blockIdx.x * (blockDim.x >> 6) + (threadIdx.x >> 6);
    const int s0 = wid * 16;
    if (s0 >= n) return;

    // B fragments: 2 ksteps x 4 ntiles, 16B per lane each
    bf16x8 bfrag[2][4];
    #pragma unroll
    for (int ks = 0; ks < 2; ++ks)
        #pragma unroll
        for (int nt = 0; nt < 4; ++nt)
            bfrag[ks][nt] = *reinterpret_cast<const bf16x8*>(
                wfrag + ((size_t)((ks * 4 + nt) * 64 + lane)) * 8);

    const int arow = s0 + (lane & 15);
    const bool vrow = arow < n;
    const float* __restrict__ fbase =
        feats + (size_t)(vrow ? arow : 0) * 64 + (lane >> 4) * 8;

    f32x4 acc[4] = {{0.f, 0.f, 0.f, 0.f}, {0.f, 0.f, 0.f, 0.f},
                    {0.f, 0.f, 0.f, 0.f}, {0.f, 0.f, 0.f, 0.f}};

    #pragma unroll
    for (int ks = 0; ks < 2; ++ks) {
        const f32x4 flo = *reinterpret_cast<const f32x4*>(fbase + ks * 32);
        const f32x4 fhi = *reinterpret_cast<const f32x4*>(fbase + ks * 32 + 4);
        bf16x8 afrag;
        afrag[0] = (short)f2bf(flo.x); afrag[1] = (short)f2bf(flo.y);
        afrag[2] = (short)f2bf(flo.z); afrag[3] = (short)f2bf(flo.w);
        afrag[4] = (short)f2bf(fhi.x); afrag[5] = (short)f2bf(fhi.y);
        afrag[6] = (short)f2bf(fhi.z); afrag[7] = (short)f2bf(fhi.w);
        #pragma unroll
        for (int nt = 0; nt < 4; ++nt)
            acc[nt] = __builtin_amdgcn_mfma_f32_16x16x32_bf16(
                afrag, bfrag[ks][nt], acc[nt], 0, 0, 0);
    }

    const int crow0 = s0 + (lane >> 4) * 4;
    const int col = lane & 15;
    #pragma unroll
    for (int nt = 0; nt < 4; ++nt) {
        const float bv = bias[nt * 16 + col];
        #pragma unroll
        for (int r = 0; r < 4; ++r) {
            const int sr = crow0 + r;
            if (sr < n)
                out[(size_t)sr * 64 + nt * 16 + col] = acc[nt][r] + bv;
        }
    }
}

// One wave per pair (grid-stride over 64 regions): out[site] += feats[nbi] @
// W[k], fp32 atomics.
__global__ __launch_bounds__(256) void conv_pairs_kernel(
    const float* __restrict__ feats, const float* __restrict__ weight,
    const uint2* __restrict__ pairs, const unsigned* __restrict__ cnts,
    unsigned rcap, float* __restrict__ out)
{
    const int lane = threadIdx.x & 63;
    const unsigned nw = (gridDim.x * blockDim.x) >> 6;
    const unsigned wid = blockIdx.x * (blockDim.x >> 6) + (threadIdx.x >> 6);
    for (unsigned r = 0; r < NREG; ++r) {
        unsigned cnt = cnts[r];
        if (cnt > rcap) cnt = rcap;
        const uint2* __restrict__ rp = pairs + (size_t)r * rcap;
        for (unsigned p = wid; p < cnt; p += nw) {
            const uint2 pr = rp[p];
            const unsigned site = pr.x & 0x3FFFFu;
            const unsigned k = pr.x >> 18;
            const unsigned nbi = pr.y;
            const float4* __restrict__ fr =
                reinterpret_cast<const float4*>(feats + (size_t)nbi * 64);
            const float* __restrict__ wk = weight + (size_t)k * 4096;
            float a0 = 0.f, a1 = 0.f, a2 = 0.f, a3 = 0.f;
            #pragma unroll
            for (int q = 0; q < 16; ++q) {
                const float4 f = fr[q];
                a0 = fmaf(f.x, wk[(4 * q + 0) * 64 + lane], a0);
                a1 = fmaf(f.y, wk[(4 * q + 1) * 64 + lane], a1);
                a2 = fmaf(f.z, wk[(4 * q + 2) * 64 + lane], a2);
                a3 = fmaf(f.w, wk[(4 * q + 3) * 64 + lane], a3);
            }
            atomicAdd(&out[(size_t)site * 64 + lane], (a0 + a1) + (a2 + a3));
        }
    }
}

extern "C" void kernel_launch(void* const* d_in, const int* in_sizes, int n_in,
                              void* d_out, int out_size, void* d_ws, size_t ws_size,
                              hipStream_t stream) {
    const float* feats  = (const float*)d_in[0];   // (N, 64)
    const int4*  coords = (const int4*)d_in[1];    // (N, 4)
    const float* weight = (const float*)d_in[2];   // (27, 64, 64)
    const float* bias   = (const float*)d_in[3];   // (64,)
    float* out = (float*)d_out;

    const int n = in_sizes[1] / 4;

    // ws layout: keys | vals | cnts (256B = 64 counters) | wfrag (8KB) | pairs
    const bool big = ws_size >= ((size_t)16 << 20);
    const int nslots = big ? (1 << 19) : (1 << 18);
    const unsigned mask = (unsigned)(nslots - 1);
    unsigned* keys = (unsigned*)d_ws;
    unsigned* vals = keys + nslots;
    unsigned* cnts = vals + nslots;
    unsigned short* wfrag = (unsigned short*)((char*)cnts + 256);
    uint2* pairs = (uint2*)((char*)wfrag + 8192);
    const size_t used = (size_t)nslots * 8 + 256 + 8192;
    size_t cap_sz = (ws_size > used) ? (ws_size - used) / sizeof(uint2) : 0;
    if (cap_sz > (size_t)(4 << 20)) cap_sz = (size_t)(4 << 20);
    const unsigned rcap = (unsigned)(cap_sz / NREG);

    {
        int blocks = (nslots + 255) / 256;
        init_table_kernel<<<blocks, 256, 0, stream>>>(keys, nslots, cnts,
                                                      weight, wfrag);
    }
    {
        int blocks = (n + 255) / 256;
        insert_kernel<<<blocks, 256, 0, stream>>>(coords, n, keys, vals, mask);
    }
    {
        int blocks = (n + 127) / 128;   // 128 sites/block, 2 threads/site
        probe_pairs_kernel<<<blocks, 256, 0, stream>>>(coords, n, keys, vals,
                                                       mask, cnts, pairs, rcap);
    }
    {
        int waves = (n + 15) / 16;
        int blocks = (waves + 3) / 4;
        conv_center_mfma<<<blocks, 256, 0, stream>>>(feats, wfrag, bias, out, n);
    }
    {
        conv_pairs_kernel<<<1024, 256, 0, stream>>>(feats, weight, pairs, cnts,
                                                    rcap, out);
    }
}

// Round 4
// 115.762 us; speedup vs baseline: 2.0263x; 1.7175x over previous
//
#include <hip/hip_runtime.h>
#include <cstdint>
#include <cstddef>

// Sparse submanifold 3x3x3 conv, C_in=C_out=64, fp32. SHAPE=(256,256,256), BS=2
// -> packed key = (b<<24)|(x<<16)|(y<<8)|z.
//
// center tap (k=13): dense 200K x 64 @ 64 x 64 GEMM via bf16 MFMA
// (16x16x32), W13 pre-packed into fragment order. Non-center taps (~31K
// hits -> ~62K pairs): probe compacts (site,k,nbi) bucketed BY TAP k into 27
// regions; conv_pairs assigns 48 blocks per region so each block streams one
// 16KB W[k] (L1-resident), fp32 FMA + atomics (math unchanged vs R0).
//
// R1: 13 offsets (mutual symmetry, emit both directions), batched MLP probe.
// R2: FAILED — 12.5K blocks x same-address reservation atomic = ~110us chain.
// R3: 2 thr/site probe + 64-way sharded counters; probe OK but conv_pairs
//     region-loop collapsed parallelism (occ 7%: only ~970 of 4096 waves
//     active, serial dependent cnts[r] loads between regions) -> 114us.
// R4(this): pairs bucketed by k at probe flush (per-k padded counters, LDS
//     histogram + scatter, LCAP 512 + rare global spill); conv_pairs gets a
//     static region per block (no region loop, full grid active) and W[k]
//     becomes L1-hit (was 1GB of L2 = 16KB/pair).

typedef __attribute__((ext_vector_type(8))) short bf16x8;
typedef __attribute__((ext_vector_type(4))) float f32x4;

static constexpr unsigned EMPTY_KEY = 0xFFFFFFFFu;
static constexpr int LCAP = 512;      // LDS-staged pairs per block (expected ~40)
static constexpr unsigned NREGION = 27;  // pair regions, indexed by tap k (13 empty)
static constexpr unsigned CPAD = 16;     // counter padding (uints): 64B apart
static constexpr int PB = 48;         // conv_pairs blocks per region

__device__ __forceinline__ unsigned hash_mix(unsigned key) {
    unsigned h = key * 0x9E3779B1u;
    h ^= h >> 15;
    return h;
}

__device__ __forceinline__ unsigned short f2bf(float x) {  // RNE fp32->bf16
    unsigned u = __builtin_bit_cast(unsigned, x);
    return (unsigned short)((u + 0x7FFFu + ((u >> 16) & 1u)) >> 16);
}

// init: clear hash keys, zero padded region counters, build W13 bf16 fragment
// table. wfrag entry e = (ks*4 + nt)*64 + lane, elem j =
// bf16(W13[ks*32+(lane>>4)*8+j][nt*16+(lane&15)]).
__global__ void init_table_kernel(unsigned* __restrict__ keys, int nslots,
                                  unsigned* __restrict__ cnts,
                                  const float* __restrict__ weight,
                                  unsigned short* __restrict__ wfrag) {
    int i = blockIdx.x * blockDim.x + threadIdx.x;
    if (i < nslots) keys[i] = EMPTY_KEY;
    if (i < 512) {
        cnts[i] = 0u;   // covers NREGION*CPAD = 432 padded counters
        const int lane = i & 63, nt = (i >> 6) & 3, ks = i >> 8;
        const float* __restrict__ w13 = weight + 13 * 4096;
        #pragma unroll
        for (int j = 0; j < 8; ++j) {
            const int k = ks * 32 + (lane >> 4) * 8 + j;
            const int n = nt * 16 + (lane & 15);
            wfrag[(size_t)i * 8 + j] = f2bf(w13[k * 64 + n]);
        }
    }
}

__global__ void insert_kernel(const int4* __restrict__ coords, int n,
                              unsigned* __restrict__ keys,
                              unsigned* __restrict__ vals, unsigned mask) {
    int i = blockIdx.x * blockDim.x + threadIdx.x;
    if (i >= n) return;
    const int4 c = coords[i];   // (b, x, y, z)
    const unsigned key = ((unsigned)c.x << 24) | ((unsigned)c.y << 16) |
                         ((unsigned)c.z << 8) | (unsigned)c.w;
    unsigned s = hash_mix(key) & mask;
    while (true) {
        unsigned prev = atomicCAS(&keys[s], EMPTY_KEY, key);
        if (prev == EMPTY_KEY) { vals[s] = (unsigned)i; break; }
        s = (s + 1) & mask;   // coords unique -> no duplicate keys
    }
}

// Two threads per site: t=0 handles offsets 0..6, t=1 handles 7..12 (of the
// 13 k<13 offsets; each hit also emits the mirror (nbi,26-k,site)).
// Phase 1 issues all first-round hash loads independently (MLP); phase 2
// resolves with a rare serial continuation. Hits staged in LDS, then flushed
// bucketed by tap k: LDS histogram -> one padded global atomic per
// (block, nonempty k) -> LDS-positioned scatter into region k of pairs.
__global__ __launch_bounds__(256) void probe_pairs_kernel(
    const int4* __restrict__ coords, int n,
    const unsigned* __restrict__ keys, const unsigned* __restrict__ vals,
    unsigned mask, unsigned* __restrict__ cnts, uint2* __restrict__ pairs,
    unsigned rcap)
{
    __shared__ unsigned lcnt;
    __shared__ unsigned lk[32], lkb[32], lkp[32];
    __shared__ uint2 lbuf[LCAP];
    if (threadIdx.x == 0) lcnt = 0u;
    if (threadIdx.x < 32) lk[threadIdx.x] = 0u;
    __syncthreads();

    const int t = threadIdx.x & 1;
    const int site = (blockIdx.x * 256 + threadIdx.x) >> 1;
    if (site < n) {
        const int4 c = coords[site];
        const int k0 = t * 7;          // t=0: k=0..6, t=1: k=7..12
        const int nk = 7 - t;          // 7 or 6 active offsets
        unsigned kv[7];
        unsigned vmask = 0u;

        // phase 1: all first-round loads in flight (no inter-iter deps)
        #pragma unroll
        for (int j = 0; j < 7; ++j) {
            const int k = k0 + j;
            const int dx = k / 9 - 1, dy = (k / 3) % 3 - 1, dz = k % 3 - 1;
            const int nx = c.y + dx, ny = c.z + dy, nz = c.w + dz;
            const bool inb = (j < nk) && (((nx | ny | nz) & ~255) == 0);
            vmask |= inb ? (1u << j) : 0u;
            const unsigned key = ((unsigned)c.x << 24) | ((unsigned)nx << 16) |
                                 ((unsigned)ny << 8) | (unsigned)nz;
            kv[j] = inb ? keys[hash_mix(key) & mask] : EMPTY_KEY;
        }

        // phase 2: resolve (recompute key/slot to keep register pressure low)
        #pragma unroll
        for (int j = 0; j < 7; ++j) {
            if (!((vmask >> j) & 1u)) continue;
            const int k = k0 + j;
            const int dx = k / 9 - 1, dy = (k / 3) % 3 - 1, dz = k % 3 - 1;
            const unsigned key = ((unsigned)c.x << 24) |
                                 ((unsigned)(c.y + dx) << 16) |
                                 ((unsigned)(c.z + dy) << 8) |
                                 (unsigned)(c.w + dz);
            unsigned s = hash_mix(key) & mask;
            unsigned kvv = kv[j];
            while (kvv != EMPTY_KEY) {
                if (kvv == key) {
                    const unsigned nbi = vals[s];
                    const uint2 p0 = make_uint2(
                        (unsigned)site | ((unsigned)k << 18), nbi);
                    const uint2 p1 = make_uint2(
                        nbi | ((unsigned)(26 - k) << 18), (unsigned)site);
                    const unsigned li = atomicAdd(&lcnt, 2u);
                    if (li + 1 < (unsigned)LCAP) {     // li even, LCAP even
                        lbuf[li] = p0;
                        lbuf[li + 1] = p1;
                    } else {                            // statistically ~never
                        const unsigned g0 = atomicAdd(&cnts[k * CPAD], 1u);
                        if (g0 < rcap) pairs[(size_t)k * rcap + g0] = p0;
                        const unsigned g1 =
                            atomicAdd(&cnts[(26 - k) * CPAD], 1u);
                        if (g1 < rcap) pairs[(size_t)(26 - k) * rcap + g1] = p1;
                    }
                    break;
                }
                s = (s + 1) & mask;
                kvv = keys[s];
            }
        }
    }

    __syncthreads();
    const unsigned nloc = lcnt < (unsigned)LCAP ? lcnt : (unsigned)LCAP;
    // per-k histogram of staged pairs
    for (unsigned i = threadIdx.x; i < nloc; i += blockDim.x)
        atomicAdd(&lk[lbuf[i].x >> 18], 1u);
    __syncthreads();
    // one padded global reservation per nonempty k
    if (threadIdx.x < NREGION) {
        const unsigned c = lk[threadIdx.x];
        lkb[threadIdx.x] = c ? atomicAdd(&cnts[threadIdx.x * CPAD], c) : 0u;
        lkp[threadIdx.x] = 0u;
    }
    __syncthreads();
    // scatter into per-k regions
    for (unsigned i = threadIdx.x; i < nloc; i += blockDim.x) {
        const uint2 e = lbuf[i];
        const unsigned kk = e.x >> 18;
        const unsigned pos = atomicAdd(&lkp[kk], 1u);
        const unsigned idx = lkb[kk] + pos;
        if (idx < rcap) pairs[(size_t)kk * rcap + idx] = e;
    }
}

// Dense center GEMM via MFMA: out = bias + feats @ W13.
// One wave per 16 sites x 64 oc. A: row=lane&15, k=(lane>>4)*8+j (+ks*32).
// B pre-packed in wfrag. C/D: col=lane&15, row=(lane>>4)*4+reg.
__global__ __launch_bounds__(256) void conv_center_mfma(
    const float* __restrict__ feats, const unsigned short* __restrict__ wfrag,
    const float* __restrict__ bias, float* __restrict__ out, int n)
{
    const int lane = threadIdx.x & 63;
    const int wid = blockIdx.x * (blockDim.x >> 6) + (threadIdx.x >> 6);
    const int s0 = wid * 16;
    if (s0 >= n) return;

    // B fragments: 2 ksteps x 4 ntiles, 16B per lane each
    bf16x8 bfrag[2][4];
    #pragma unroll
    for (int ks = 0; ks < 2; ++ks)
        #pragma unroll
        for (int nt = 0; nt < 4; ++nt)
            bfrag[ks][nt] = *reinterpret_cast<const bf16x8*>(
                wfrag + ((size_t)((ks * 4 + nt) * 64 + lane)) * 8);

    const int arow = s0 + (lane & 15);
    const bool vrow = arow < n;
    const float* __restrict__ fbase =
        feats + (size_t)(vrow ? arow : 0) * 64 + (lane >> 4) * 8;

    f32x4 acc[4] = {{0.f, 0.f, 0.f, 0.f}, {0.f, 0.f, 0.f, 0.f},
                    {0.f, 0.f, 0.f, 0.f}, {0.f, 0.f, 0.f, 0.f}};

    #pragma unroll
    for (int ks = 0; ks < 2; ++ks) {
        const f32x4 flo = *reinterpret_cast<const f32x4*>(fbase + ks * 32);
        const f32x4 fhi = *reinterpret_cast<const f32x4*>(fbase + ks * 32 + 4);
        bf16x8 afrag;
        afrag[0] = (short)f2bf(flo.x); afrag[1] = (short)f2bf(flo.y);
        afrag[2] = (short)f2bf(flo.z); afrag[3] = (short)f2bf(flo.w);
        afrag[4] = (short)f2bf(fhi.x); afrag[5] = (short)f2bf(fhi.y);
        afrag[6] = (short)f2bf(fhi.z); afrag[7] = (short)f2bf(fhi.w);
        #pragma unroll
        for (int nt = 0; nt < 4; ++nt)
            acc[nt] = __builtin_amdgcn_mfma_f32_16x16x32_bf16(
                afrag, bfrag[ks][nt], acc[nt], 0, 0, 0);
    }

    const int crow0 = s0 + (lane >> 4) * 4;
    const int col = lane & 15;
    #pragma unroll
    for (int nt = 0; nt < 4; ++nt) {
        const float bv = bias[nt * 16 + col];
        #pragma unroll
        for (int r = 0; r < 4; ++r) {
            const int sr = crow0 + r;
            if (sr < n)
                out[(size_t)sr * 64 + nt * 16 + col] = acc[nt][r] + bv;
        }
    }
}

// 48 blocks per tap region; one wave per pair (grid-stride within region).
// All waves of a block stream the same 16KB W[k] -> L1-resident after the
// first pair. fp32 FMA + atomics (bit-identical math to R0's pairs path).
__global__ __launch_bounds__(256) void conv_pairs_kernel(
    const float* __restrict__ feats, const float* __restrict__ weight,
    const uint2* __restrict__ pairs, const unsigned* __restrict__ cnts,
    unsigned rcap, float* __restrict__ out)
{
    const int lane = threadIdx.x & 63;
    int r = blockIdx.x / PB;
    r += (r >= 13);                     // taps 0..12,14..26
    unsigned cnt = cnts[r * CPAD];
    if (cnt > rcap) cnt = rcap;
    if (cnt == 0) return;
    const uint2* __restrict__ rp = pairs + (size_t)r * rcap;
    const float* __restrict__ wk = weight + (size_t)r * 4096;
    const unsigned wloc = (blockIdx.x % PB) * 4 + (threadIdx.x >> 6);
    for (unsigned p = wloc; p < cnt; p += (unsigned)(PB * 4)) {
        const uint2 pr = rp[p];
        const unsigned site = pr.x & 0x3FFFFu;
        const unsigned nbi = pr.y;
        const float4* __restrict__ fr =
            reinterpret_cast<const float4*>(feats + (size_t)nbi * 64);
        float a0 = 0.f, a1 = 0.f, a2 = 0.f, a3 = 0.f;
        #pragma unroll
        for (int q = 0; q < 16; ++q) {
            const float4 f = fr[q];
            a0 = fmaf(f.x, wk[(4 * q + 0) * 64 + lane], a0);
            a1 = fmaf(f.y, wk[(4 * q + 1) * 64 + lane], a1);
            a2 = fmaf(f.z, wk[(4 * q + 2) * 64 + lane], a2);
            a3 = fmaf(f.w, wk[(4 * q + 3) * 64 + lane], a3);
        }
        atomicAdd(&out[(size_t)site * 64 + lane], (a0 + a1) + (a2 + a3));
    }
}

extern "C" void kernel_launch(void* const* d_in, const int* in_sizes, int n_in,
                              void* d_out, int out_size, void* d_ws, size_t ws_size,
                              hipStream_t stream) {
    const float* feats  = (const float*)d_in[0];   // (N, 64)
    const int4*  coords = (const int4*)d_in[1];    // (N, 4)
    const float* weight = (const float*)d_in[2];   // (27, 64, 64)
    const float* bias   = (const float*)d_in[3];   // (64,)
    float* out = (float*)d_out;

    const int n = in_sizes[1] / 4;

    // ws layout: keys | vals | cnts (2KB = 27 padded counters) | wfrag (8KB)
    //            | pairs (27 regions x rcap)
    const bool big = ws_size >= ((size_t)16 << 20);
    const int nslots = big ? (1 << 19) : (1 << 18);
    const unsigned mask = (unsigned)(nslots - 1);
    unsigned* keys = (unsigned*)d_ws;
    unsigned* vals = keys + nslots;
    unsigned* cnts = vals + nslots;
    unsigned short* wfrag = (unsigned short*)((char*)cnts + 2048);
    uint2* pairs = (uint2*)((char*)wfrag + 8192);
    const size_t used = (size_t)nslots * 8 + 2048 + 8192;
    size_t cap_sz = (ws_size > used) ? (ws_size - used) / sizeof(uint2) : 0;
    if (cap_sz > (size_t)(4 << 20)) cap_sz = (size_t)(4 << 20);
    const unsigned rcap = (unsigned)(cap_sz / NREGION);

    {
        int blocks = (nslots + 255) / 256;
        init_table_kernel<<<blocks, 256, 0, stream>>>(keys, nslots, cnts,
                                                      weight, wfrag);
    }
    {
        int blocks = (n + 255) / 256;
        insert_kernel<<<blocks, 256, 0, stream>>>(coords, n, keys, vals, mask);
    }
    {
        int blocks = (n + 127) / 128;   // 128 sites/block, 2 threads/site
        probe_pairs_kernel<<<blocks, 256, 0, stream>>>(coords, n, keys, vals,
                                                       mask, cnts, pairs, rcap);
    }
    {
        int waves = (n + 15) / 16;
        int blocks = (waves + 3) / 4;
        conv_center_mfma<<<blocks, 256, 0, stream>>>(feats, wfrag, bias, out, n);
    }
    {
        conv_pairs_kernel<<<26 * PB, 256, 0, stream>>>(feats, weight, pairs,
                                                       cnts, rcap, out);
    }
}